// Round 8
// baseline (202.736 us; speedup 1.0000x reference)
//
#include <hip/hip_runtime.h>
#include <stdint.h>

// CIN forward, MI355X. R8 = R7 skeleton + scalarized W addressing:
// readfirstlane'd wave coords -> W bases in SGPRs; K-loop walks a uniform
// rolling pointer (SALU s_add), per-load offsets are 13-bit immediates, only
// a loop-invariant lane*16B VGPR offset stays vector. R7's VALUBusy 57% was
// ~60% per-load 64-bit VGPR address chains. hv reads b32->b64 (4 ch/read).
// Depth-2 slot rotation + sched_barrier(0) kept (R7-proven). 512 thr,
// 2 batches/block, grid 512; 16x16x32 f16 MFMA, 8 acc chains/wave.

typedef __attribute__((ext_vector_type(8))) _Float16 f16x8;
typedef __attribute__((ext_vector_type(2))) _Float16 f16x2;
typedef __attribute__((ext_vector_type(4))) float f32x4;
typedef __attribute__((ext_vector_type(4))) int i32x4;

union AB {
  i32x4 i;
  f16x8 h;
  uint32_t u[4];
};

static __device__ __forceinline__ uint32_t pkmul(uint32_t a, uint32_t b) {
  f16x2 r = __builtin_bit_cast(f16x2, a) * __builtin_bit_cast(f16x2, b);
  return __builtin_bit_cast(uint32_t, r);  // one v_pk_mul_f16
}
static __device__ __forceinline__ uint32_t pkcvt(float a, float b) {
  return __builtin_bit_cast(uint32_t, __builtin_amdgcn_cvt_pkrtz(a, b));
}

#define HP 136  // hT row: 128 ch + 8 pad (272B stride; pad also absorbs
                // the pipeline's tail hv prefetch reads -> always in-bounds)

__global__ __launch_bounds__(512, 4) void cin_main(
    const float* __restrict__ x, const uint16_t* __restrict__ wp,
    const float* __restrict__ bias0, const float* __restrict__ bias1,
    const float* __restrict__ bias2, float* __restrict__ out) {
  __shared__ __align__(16) uint16_t hT[2][64][HP];  // [batch][d][chan] fp16

  const int tid = threadIdx.x;
  const int w = tid >> 6, lane = tid & 63;
  const int p  = __builtin_amdgcn_readfirstlane(w >> 2);  // batch (scalar)
  const int wg = __builtin_amdgcn_readfirstlane(w & 3);   // o-tile pair (scalar)
  const int q = lane >> 4;   // k-quad: B row k = q*8+j; C row o = q*4+r
  const int i = lane & 15;   // d within tile (B/C col); A row o (mod 16)
  const int bb = blockIdx.x * 2;

  // ---- stage x -> hT[p][d][m] fp16 (layer-0 h == x; 32 channels)
  for (int e = tid; e < 4096; e += 512) {
    int p2 = e >> 11, m = (e >> 6) & 31, d = e & 63;
    hT[p2][d][m] =
        __builtin_bit_cast(uint16_t, (_Float16)x[(size_t)(bb + p2) * 2048 + m * 64 + d]);
  }
  __syncthreads();

  // ---- x B-frags (loop-invariant): xf[t].j = x[m=q*8+j][d=t*16+i]
  AB xf[4];
#pragma unroll
  for (int t = 0; t < 4; ++t)
    xf[t].i = *(const i32x4*)&hT[p][t * 16 + i][q * 8];  // ds_read_b128

  f32x4 acc[4][2];           // [t][g] : 8 independent chains (AGPRs)
  const int loff = lane * 8; // uint16-elem offset: the ONLY vector addr part

#pragma unroll
  for (int L = 0; L < 3; ++L) {
    const int Kch = (L == 0) ? 32 : 128;
    const uint16_t* wl = (L == 0) ? wp : (L == 1) ? wp + 131072 : wp + 655360;
    const float* bias = (L == 0) ? bias0 : (L == 1) ? bias1 : bias2;

    // uniform (SGPR) W bases; frag(ot,c) at (ot*Kch + c)*512 elems
    const uint16_t* wb0 = wl + (size_t)(2 * wg + 0) * Kch * 512;
    const uint16_t* wb1 = wl + (size_t)(2 * wg + 1) * Kch * 512;

#pragma unroll
    for (int t = 0; t < 4; ++t) {
      acc[t][0] = (f32x4){0.f, 0.f, 0.f, 0.f};
      acc[t][1] = (f32x4){0.f, 0.f, 0.f, 0.f};
    }

    AB wbuf[2][2][2];  // [slot][cc][g] : 32 VGPRs, depth-2 rotation
    uint2 hvA[4], hvB[4];
    const uint16_t* hrow[4];  // 32-bit LDS pointers, advance +8B per read
#pragma unroll
    for (int t = 0; t < 4; ++t) hrow[t] = &hT[p][t * 16 + i][0];

    // read 4 channels of h per t (ds_read_b64), then advance
    auto loadHv = [&](uint2 (&hv)[4]) {
#pragma unroll
      for (int t = 0; t < 4; ++t) hv[t] = *(const uint2*)hrow[t];
#pragma unroll
      for (int t = 0; t < 4; ++t) hrow[t] += 4;
    };
    // slot load: uniform base wc + imm offsets {0,1024} or {2048,3072} B
    auto loadSlot = [&](int s, const uint16_t* wc0, const uint16_t* wc1, int off) {
      wbuf[s][0][0].i = *(const i32x4*)(wc0 + off + loff);
      wbuf[s][0][1].i = *(const i32x4*)(wc1 + off + loff);
      wbuf[s][1][0].i = *(const i32x4*)(wc0 + off + 512 + loff);
      wbuf[s][1][1].i = *(const i32x4*)(wc1 + off + 512 + loff);
    };
    auto computePair = [&](int s, const uint2 (&hv)[4], int hiSel) {
#pragma unroll
      for (int cc = 0; cc < 2; ++cc) {
        const uint32_t selmask = cc ? 0x03020302u : 0x01000100u;
#pragma unroll
        for (int t = 0; t < 4; ++t) {
          uint32_t word = hiSel ? hv[t].y : hv[t].x;
          uint32_t hd = __builtin_amdgcn_perm(word, word, selmask);
          AB bf;  // B-frag: P[c*32 + q*8+j][d] = h[c,d] * x[q*8+j,d]
#pragma unroll
          for (int k = 0; k < 4; ++k) bf.u[k] = pkmul(hd, xf[t].u[k]);
          acc[t][0] = __builtin_amdgcn_mfma_f32_16x16x32_f16(
              wbuf[s][cc][0].h, bf.h, acc[t][0], 0, 0, 0);
          acc[t][1] = __builtin_amdgcn_mfma_f32_16x16x32_f16(
              wbuf[s][cc][1].h, bf.h, acc[t][1], 0, 0, 0);
        }
      }
    };

    // prologue: slot0 = ch{0,1}, slot1 = ch{2,3}; wc points at ch4
    loadSlot(0, wb0, wb1, 0);
    loadSlot(1, wb0, wb1, 1024);
    const uint16_t* wc0 = wb0 + 2048;
    const uint16_t* wc1 = wb1 + 2048;
    loadHv(hvA);  // ch 0..3
    __builtin_amdgcn_sched_barrier(0);

    // invariant at loop head: slots hold pairs (c0, c0+2); wc -> ch c0+4
#pragma unroll 1
    for (int c0 = 0; c0 < Kch; c0 += 8) {
      // body 1: pairs (c0, c0+2) via hvA; refill slots with ch c0+4..c0+7
      loadHv(hvB);  // ch c0+4..c0+7
      computePair(0, hvA, 0);
      loadSlot(0, wc0, wc1, 0);
      __builtin_amdgcn_sched_barrier(0);
      computePair(1, hvA, 1);
      loadSlot(1, wc0, wc1, 1024);
      __builtin_amdgcn_sched_barrier(0);
      bool adv1 = (c0 + 8) < Kch;       // scalar select (wrap -> reload ch0-3,
      wc0 = adv1 ? wc0 + 2048 : wb0;    //  never consumed)
      wc1 = adv1 ? wc1 + 2048 : wb1;
      // body 2: pairs (c0+4, c0+6) via hvB; refill ch c0+8..c0+11
      loadHv(hvA);  // tail call reads row pad (in-bounds garbage, unused)
      computePair(0, hvB, 0);
      loadSlot(0, wc0, wc1, 0);
      __builtin_amdgcn_sched_barrier(0);
      computePair(1, hvB, 1);
      loadSlot(1, wc0, wc1, 1024);
      __builtin_amdgcn_sched_barrier(0);
      bool adv2 = (c0 + 16) <= Kch;
      wc0 = adv2 ? wc0 + 2048 : wb0;
      wc1 = adv2 ? wc1 + 2048 : wb1;
    }

    // ---- bias + ReLU (C layout: o = ot*16 + q*4 + r, d = t*16 + i)
    f32x4 bv[2];
    bv[0] = *(const f32x4*)(bias + (2 * wg + 0) * 16 + q * 4);
    bv[1] = *(const f32x4*)(bias + (2 * wg + 1) * 16 + q * 4);
#pragma unroll
    for (int t = 0; t < 4; ++t)
#pragma unroll
      for (int g = 0; g < 2; ++g)
#pragma unroll
        for (int r = 0; r < 4; ++r)
          acc[t][g][r] = fmaxf(acc[t][g][r] + bv[g][r], 0.f);

    if (L < 2) {
      __syncthreads();  // all waves done READING hT before overwrite
#pragma unroll
      for (int t = 0; t < 4; ++t)
#pragma unroll
        for (int g = 0; g < 2; ++g) {
          uint2 pk;  // next-layer h channels o = (2wg+g)*16 + q*4 + r
          pk.x = pkcvt(acc[t][g][0], acc[t][g][1]);
          pk.y = pkcvt(acc[t][g][2], acc[t][g][3]);
          *(uint2*)&hT[p][t * 16 + i][(2 * wg + g) * 16 + q * 4] = pk;
        }
    }

    // d-sum: in-register over t, then xor-shuffle the 16 i-lanes
#pragma unroll
    for (int g = 0; g < 2; ++g)
#pragma unroll
      for (int r = 0; r < 4; ++r) {
        float s = acc[0][g][r] + acc[1][g][r] + acc[2][g][r] + acc[3][g][r];
        s += __shfl_xor(s, 1);
        s += __shfl_xor(s, 2);
        s += __shfl_xor(s, 4);
        s += __shfl_xor(s, 8);
        if (i == 0)
          out[(size_t)(bb + p) * 384 + L * 128 + (2 * wg + g) * 16 + q * 4 + r] = s;
      }

    if (L < 2) __syncthreads();  // hT writes visible before next K-loop
  }
}

// One pack kernel for all 3 layers. Reads coalesced along k; writes fp16
// frags: dst elem (ot*Kch+c)*512 + q*128 + i*8  (layout verified in R3/R7).
__global__ void pack_w_all(const float* __restrict__ W0, const float* __restrict__ W1,
                           const float* __restrict__ W2, uint16_t* __restrict__ Wp) {
  int blk = blockIdx.x;
  const float* W;
  uint16_t* dst;
  int kshift;
  if (blk < 64)       { W = W0; dst = Wp;          kshift = 5; }
  else if (blk < 320) { W = W1; dst = Wp + 131072; kshift = 7; blk -= 64; }
  else                { W = W2; dst = Wp + 655360; kshift = 7; blk -= 320; }
  int idx = blk * 256 + threadIdx.x;
  int Kq = 1 << (kshift + 2);        // Kch*4 = K/8
  int o = idx >> (kshift + 2);
  int kq = idx & (Kq - 1);
  int c = kq >> 2, q = kq & 3;
  int ot = o >> 4, ii = o & 15;
  const float* src = W + ((size_t)o << (kshift + 5)) + kq * 8;
  uint4 val;
  val.x = pkcvt(src[0], src[1]);
  val.y = pkcvt(src[2], src[3]);
  val.z = pkcvt(src[4], src[5]);
  val.w = pkcvt(src[6], src[7]);
  *(uint4*)(dst + ((((size_t)ot << kshift) + c) << 9) + (q << 7) + (ii << 3)) = val;
}

extern "C" void kernel_launch(void* const* d_in, const int* in_sizes, int n_in,
                              void* d_out, int out_size, void* d_ws, size_t ws_size,
                              hipStream_t stream) {
  (void)in_sizes; (void)n_in; (void)out_size; (void)ws_size;
  const float* x  = (const float*)d_in[0];
  const float* W0 = (const float*)d_in[1];
  const float* b0 = (const float*)d_in[2];
  const float* W1 = (const float*)d_in[3];
  const float* b1 = (const float*)d_in[4];
  const float* W2 = (const float*)d_in[5];
  const float* b2 = (const float*)d_in[6];
  uint16_t* wpacked = (uint16_t*)d_ws;  // 2.25 MB of ws

  hipLaunchKernelGGL(pack_w_all, dim3(576), dim3(256), 0, stream, W0, W1, W2, wpacked);
  hipLaunchKernelGGL(cin_main, dim3(512), dim3(512), 0, stream,
                     x, wpacked, b0, b1, b2, (float*)d_out);
}